// Round 10
// baseline (135.779 us; speedup 1.0000x reference)
//
#include <hip/hip_runtime.h>
#include <stdint.h>

// SAGEConv (mean aggr, no bias): out = segment_mean(x[src], dst) @ W_l + x @ W_r
// Pipeline (memset + 2 kernels):
//   memset : cursorB[1024] = 0 (4 KB)
//   k_prep : block-role split:
//              [0,EB)    : partition edges into padded dst-buckets (dst>>7):
//                          LDS histogram -> ONE global atomicAdd per
//                          (block,bucket) range-reserve -> direct scatter via
//                          LDS cursors. No scan, no staging, 4 KB LDS.
//                          (r6: per-EDGE global cursors disaster; r8: staging
//                           +scan deletion proven neutral-to-better.)
//              [EB,EB+8) : Wl/Wr transpose -> bf16
//              [EB+8,..) : x -> bf16, 4 independent float4/thread (MLP fix:
//                          1 load/thread = wave-churn latency-bound since r0)
//   k_fused: per bucket (128 nodes): stream packed edges, LDS fixed-point
//            accumulation via PAIRED ds_add_u64 (fp32 LDS atomicAdd is a
//            CAS-loop disaster on gfx950; u64 int add is native)
//            -> mean -> bf16 -> MFMA GEMM: out = mean@Wl + x@Wr
//            (r7 config verbatim: NPB=128/512thr beats NPB=64/256thr by
//             ~10us — r5/r8 cross-check.)
//
// Magic-number fixed-point (validated r5-r8): bits(fmaf(xf,2^19,1.5*2^23)) =
// 0x4B400000 + round_ne(xf*2^19). lo half of u64: masked 23 bits (per-addend
// bias 2^22); hi half keeps 0x4B400000, wraps mod 2^32 (removed as deg*const
// at epilogue). lo-half sum <= deg*2^23 < 2^32 for deg < 512 (max ~45 here).
// Quantization 2^-19 ~ 2e-6 << 0.03 tol; integer adds commute -> bit-stable.
//
// Geometry: NPB=128 -> accI[128][66] = 33.8 KB LDS; 512 thr (8 waves) ->
// 4 blocks/CU = 32 waves/CU. Pairs packed u32 = src | (dl<<24).

#define FDIM 64
#define NPB 128     // nodes per bucket (bucket = dst>>7)
#define ACCW 66     // padded int row stride (even: u64-aligned rows)
#define MAXBKT 1024 // bucket bound (782 used at N=100000)
#define PART_T 4096
#define CAP 2048    // per-bucket capacity (avg 1535, sd ~39 -> +13 sigma)
#define CAPSH 11
#define FPS 524288.0f        // 2^19
#define FPINV (1.0f / 524288.0f)
#define MAGICF 12582912.0f   // 1.5 * 2^23
#define LOB 0x00400000u      // per-addend lo bias 2^22
#define HIB 0x4B400000u      // per-addend hi constant (bits of MAGICF)

typedef __attribute__((ext_vector_type(8))) short bf16x8;
typedef __attribute__((ext_vector_type(4))) float f32x4;

__device__ inline ushort f2b(float v) {
  union { float f; uint32_t u; } c; c.f = v;
  return (ushort)((c.u + 0x7FFF + ((c.u >> 16) & 1)) >> 16);  // RNE
}
__device__ inline float b2f(ushort h) {
  union { uint32_t u; float f; } c; c.u = ((uint32_t)h) << 16;
  return c.f;
}
__device__ inline uint32_t fxbits(float xf) {  // 0x4B400000 + round_ne(xf*2^19)
  union { float f; uint32_t u; } c;
  c.f = fmaf(xf, FPS, MAGICF);
  return c.u;
}

// ---- 1: merged prep: partition (blocks 0..EB-1) | W^T (8) | x->bf16 (rest) ----
__global__ __launch_bounds__(512) void k_prep(const float* __restrict__ x,
                                              const float* __restrict__ Wl,
                                              const float* __restrict__ Wr,
                                              const int* __restrict__ esrc,
                                              const int* __restrict__ edst,
                                              int* __restrict__ cursorB,
                                              uint32_t* __restrict__ pairs,
                                              ushort* __restrict__ xb,
                                              ushort* __restrict__ WlT,
                                              ushort* __restrict__ WrT, int E,
                                              int EB, int xquads) {
  __shared__ int cnt[MAXBKT];  // histogram -> (reused) global write cursor
  const int bid = blockIdx.x;
  const int t = threadIdx.x;

  if (bid >= EB) {
    if (bid < EB + 8) {  // W transpose: 8 blocks x 512 = 4096 elements
      const int idx = (bid - EB) * 512 + t;
      const int f = idx >> 6, k = idx & 63;
      WlT[f * 64 + k] = f2b(Wl[k * 64 + f]);
      WrT[f * 64 + k] = f2b(Wr[k * 64 + f]);
    } else {  // x -> bf16: 4 independent float4 per thread (MLP)
      const int base = (bid - EB - 8) * 2048 + t;
      float4 v[4];
      int idx[4];
#pragma unroll
      for (int k = 0; k < 4; ++k) {
        idx[k] = base + k * 512;
        if (idx[k] < xquads) v[k] = ((const float4*)x)[idx[k]];
      }
#pragma unroll
      for (int k = 0; k < 4; ++k) {
        if (idx[k] < xquads) {
          ushort4 o;
          o.x = f2b(v[k].x); o.y = f2b(v[k].y);
          o.z = f2b(v[k].z); o.w = f2b(v[k].w);
          ((ushort4*)xb)[idx[k]] = o;
        }
      }
    }
    return;
  }

  // ---- partition: histogram -> range-reserve -> direct scatter ----
  const int base = bid * PART_T;
  cnt[t] = 0;
  cnt[t + 512] = 0;
  __syncthreads();

  int s[8], d[8];
#pragma unroll
  for (int i = 0; i < 8; ++i) {
    const int e = base + i * 512 + t;
    if (e < E) {
      s[i] = esrc[e];
      d[i] = edst[e];
      atomicAdd(&cnt[d[i] >> 7], 1);
    } else {
      d[i] = -1;
    }
  }
  __syncthreads();

  // reserve global ranges: one global atomic per (block, nonzero bucket);
  // cnt[b] becomes the absolute write cursor for this block's share.
#pragma unroll
  for (int i = 0; i < 2; ++i) {
    const int b = t + i * 512;
    const int cb = cnt[b];
    if (cb > 0) cnt[b] = (b << CAPSH) + atomicAdd(&cursorB[b], cb);
  }
  __syncthreads();  // compiler emits vmcnt(0) before s_barrier -> bases valid

#pragma unroll
  for (int i = 0; i < 8; ++i) {
    if (d[i] >= 0) {
      const int slot = atomicAdd(&cnt[d[i] >> 7], 1);
      pairs[slot] = (uint32_t)s[i] | ((uint32_t)(d[i] & (NPB - 1)) << 24);
    }
  }
}

// ---- 2: fused streaming aggregation + MFMA GEMM (128 nodes / block) ----
// Gather: lanes c=t&15 (8B feature slice), slot=t>>4 (edge slot 0..31);
// 32 edges/pass x U=8 unroll. Per edge-lane: 2 paired ds_add_u64
// (magic-fma fixed-point). Main loop unpredicated (full 256-edge passes);
// single predicated tail pass. MFMA: wave w = 16-node tile; 4 f-slices.
__global__ __launch_bounds__(512, 8) void k_fused(
    const ushort* __restrict__ xb, const int* __restrict__ cursorB,
    const uint32_t* __restrict__ pairs, const ushort* __restrict__ WlT,
    const ushort* __restrict__ WrT, float* __restrict__ out, int n_nodes) {
  __shared__ int accI[NPB][ACCW];
  __shared__ int deg[NPB];
  const int b = blockIdx.x;
  const int t = threadIdx.x;
  const int wave = t >> 6;
  const int lane = t & 63;
  const int c = t & 15;
  const int slot = t >> 4;  // 0..31
  const int nodebase = b * NPB;

  {
    int2* af = (int2*)&accI[0][0];
    for (int i = t; i < NPB * ACCW / 2; i += 512) af[i] = make_int2(0, 0);
    if (t < NPB) deg[t] = 0;
  }
  __syncthreads();

  const int rbase = b << CAPSH;
  const int ecnt = cursorB[b];
  const int full = ecnt & ~255;  // steady-state passes: all 256 edges valid

  for (int base0 = 0; base0 < full; base0 += 256) {
    uint32_t p[8];
#pragma unroll
    for (int u = 0; u < 8; ++u) p[u] = pairs[rbase + base0 + u * 32 + slot];
    ushort4 h[8];
#pragma unroll
    for (int u = 0; u < 8; ++u)
      h[u] = *(const ushort4*)(xb + (size_t)(p[u] & 0xFFFFFFu) * FDIM +
                               (c << 2));
#pragma unroll
    for (int u = 0; u < 8; ++u) {
      const int dl = p[u] >> 24;
      unsigned long long* a64 = (unsigned long long*)&accI[dl][c << 2];
      const uint32_t lo0 = fxbits(b2f(h[u].x)) & 0x007FFFFFu;
      const uint32_t hi0 = fxbits(b2f(h[u].y));
      const uint32_t lo1 = fxbits(b2f(h[u].z)) & 0x007FFFFFu;
      const uint32_t hi1 = fxbits(b2f(h[u].w));
      atomicAdd(a64, ((unsigned long long)hi0 << 32) | lo0);
      atomicAdd(a64 + 1, ((unsigned long long)hi1 << 32) | lo1);
      if (c == 0) atomicAdd(&deg[dl], 1);
    }
  }
  // tail pass (< 256 edges), predicated
  if (full < ecnt) {
    uint32_t p[8];
#pragma unroll
    for (int u = 0; u < 8; ++u) {
      const int e = full + u * 32 + slot;
      p[u] = (e < ecnt) ? pairs[rbase + e] : 0xFFFFFFFFu;
    }
    ushort4 h[8];
#pragma unroll
    for (int u = 0; u < 8; ++u)
      if (p[u] != 0xFFFFFFFFu)
        h[u] = *(const ushort4*)(xb + (size_t)(p[u] & 0xFFFFFFu) * FDIM +
                                 (c << 2));
#pragma unroll
    for (int u = 0; u < 8; ++u)
      if (p[u] != 0xFFFFFFFFu) {
        const int dl = p[u] >> 24;
        unsigned long long* a64 = (unsigned long long*)&accI[dl][c << 2];
        const uint32_t lo0 = fxbits(b2f(h[u].x)) & 0x007FFFFFu;
        const uint32_t hi0 = fxbits(b2f(h[u].y));
        const uint32_t lo1 = fxbits(b2f(h[u].z)) & 0x007FFFFFu;
        const uint32_t hi1 = fxbits(b2f(h[u].w));
        atomicAdd(a64, ((unsigned long long)hi0 << 32) | lo0);
        atomicAdd(a64 + 1, ((unsigned long long)hi1 << 32) | lo1);
        if (c == 0) atomicAdd(&deg[dl], 1);
      }
  }
  __syncthreads();

  // MFMA phase: 8 waves x 16-node tiles
  {
    const int m = lane & 15;
    const int quad = lane >> 4;
    const int lrow = wave * 16 + m;
    const int node = nodebase + lrow;
    const int dg = deg[lrow];
    const uint32_t dbl = (uint32_t)dg * LOB;  // lo-half bias total
    const uint32_t dbh = (uint32_t)dg * HIB;  // hi-half const total (wraps ok)
    const float inv = FPINV / (float)max(dg, 1);
    bf16x8 am0, am1;
#pragma unroll
    for (int j = 0; j < 8; ++j) {
      const int k = quad * 8 + j;  // comp parity = j&1 (quad*8 even)
      const uint32_t db = (j & 1) ? dbh : dbl;
      const int s0 = (int)((uint32_t)accI[lrow][k] - db);
      const int s1 = (int)((uint32_t)accI[lrow][32 + k] - db);
      am0[j] = (short)f2b((float)s0 * inv);
      am1[j] = (short)f2b((float)s1 * inv);
    }
    const int arow = min(node, n_nodes - 1);
    bf16x8 ax0 = *(const bf16x8*)(xb + (size_t)arow * FDIM + quad * 8);
    bf16x8 ax1 = *(const bf16x8*)(xb + (size_t)arow * FDIM + 32 + quad * 8);
#pragma unroll
    for (int fs = 0; fs < 4; ++fs) {
      const int f = fs * 16 + m;
      bf16x8 bl0 = *(const bf16x8*)(WlT + (size_t)f * FDIM + quad * 8);
      bf16x8 bl1 = *(const bf16x8*)(WlT + (size_t)f * FDIM + 32 + quad * 8);
      bf16x8 br0 = *(const bf16x8*)(WrT + (size_t)f * FDIM + quad * 8);
      bf16x8 br1 = *(const bf16x8*)(WrT + (size_t)f * FDIM + 32 + quad * 8);
      f32x4 acc4 = {0.f, 0.f, 0.f, 0.f};
      acc4 = __builtin_amdgcn_mfma_f32_16x16x32_bf16(am0, bl0, acc4, 0, 0, 0);
      acc4 = __builtin_amdgcn_mfma_f32_16x16x32_bf16(am1, bl1, acc4, 0, 0, 0);
      acc4 = __builtin_amdgcn_mfma_f32_16x16x32_bf16(ax0, br0, acc4, 0, 0, 0);
      acc4 = __builtin_amdgcn_mfma_f32_16x16x32_bf16(ax1, br1, acc4, 0, 0, 0);
#pragma unroll
      for (int r = 0; r < 4; ++r) {
        const int onode = nodebase + wave * 16 + quad * 4 + r;
        if (onode < n_nodes) out[(size_t)onode * FDIM + fs * 16 + m] = acc4[r];
      }
    }
  }
}

extern "C" void kernel_launch(void* const* d_in, const int* in_sizes, int n_in,
                              void* d_out, int out_size, void* d_ws, size_t ws_size,
                              hipStream_t stream) {
  const float* x = (const float*)d_in[0];
  const int* edge_index = (const int*)d_in[1];
  const float* Wl = (const float*)d_in[2];
  const float* Wr = (const float*)d_in[3];
  float* out = (float*)d_out;

  const int n_nodes = in_sizes[0] / FDIM;  // 100000
  const int n_edges = in_sizes[1] / 2;     // 1200000
  const int* e_src = edge_index;
  const int* e_dst = edge_index + n_edges;

  const int NB2 = (n_nodes + NPB - 1) / NPB;  // 782

  // ws layout
  int* cursorB = (int*)d_ws;  // MAXBKT
  uint32_t* pairs = (uint32_t*)(cursorB + MAXBKT);  // (NB2+1)*CAP u32
  ushort* xbuf = (ushort*)(((uintptr_t)(pairs + ((size_t)(NB2 + 1) << CAPSH)) +
                            15) & ~(uintptr_t)15);  // N*64 bf16
  ushort* WlT = xbuf + (size_t)n_nodes * FDIM;      // 4096
  ushort* WrT = WlT + FDIM * FDIM;                  // 4096

  const int xquads = n_nodes * (FDIM / 4);         // 1.6M float4 units
  const int XB2 = (xquads + 2047) / 2048;          // 782 (4 float4 / thread)
  const int EB = (n_edges + PART_T - 1) / PART_T;  // 293

  hipMemsetAsync(cursorB, 0, MAXBKT * sizeof(int), stream);
  k_prep<<<EB + 8 + XB2, 512, 0, stream>>>(x, Wl, Wr, e_src, e_dst, cursorB,
                                           pairs, xbuf, WlT, WrT, n_edges, EB,
                                           xquads);
  k_fused<<<NB2, 512, 0, stream>>>(xbuf, cursorB, pairs, WlT, WrT, out, n_nodes);
}